// Round 1
// baseline (744.753 us; speedup 1.0000x reference)
//
#include <hip/hip_runtime.h>
#include <hip/hip_bf16.h>

// GraphConv: masked single-head attention, B=16, N=2048, D=64.
// Inputs (fp32 unless noted): x[B,N,64], adj[B,N,N] int32, Wq,bq,Wk,bk,Wv,bv,Wo,bo (64x64/64), Wl[128,64], bl[64]
// Outputs (fp32, concat): y[B,N,64] then attn[B,N,N]

#define NB 16
#define NN 2048
#define DI 64

using s8v  = __attribute__((ext_vector_type(8))) short;   // 8 bf16 (4 VGPR) MFMA frag
using f32x4 = __attribute__((ext_vector_type(4))) float;

__device__ __forceinline__ ushort f2bf(float f) {
    __hip_bfloat16 h = __float2bfloat16(f);   // RNE; compiler emits v_cvt_pk where possible
    return *reinterpret_cast<ushort*>(&h);
}
__device__ __forceinline__ float bf2f(ushort u) {
    union { uint32_t u; float f; } v; v.u = ((uint32_t)u) << 16;
    return v.f;
}

// ---------------- Kernel 1: q,k (split bf16 hi/lo, row-major) and vT (bf16, [b][d][n]) ----------------
__global__ __launch_bounds__(256)
void qkv_kernel(const float* __restrict__ x,
                const float* __restrict__ Wq, const float* __restrict__ bq,
                const float* __restrict__ Wk, const float* __restrict__ bk,
                const float* __restrict__ Wv, const float* __restrict__ bv,
                ushort* __restrict__ qh, ushort* __restrict__ ql,
                ushort* __restrict__ kh, ushort* __restrict__ kl,
                ushort* __restrict__ vt)
{
    __shared__ float xs[32 * 65];            // padded: bank-conflict-free transpose
    const int t  = threadIdx.x;
    const int r0 = blockIdx.x * 32;          // global row (32 rows/block, batch-aligned: 2048%32==0)
    for (int idx = t; idx < 2048; idx += 256)
        xs[(idx >> 6) * 65 + (idx & 63)] = x[(size_t)r0 * 64 + idx];
    __syncthreads();

    const int col = t & 63;
    const int rg  = (t >> 6) * 8;            // 8 rows per thread-group

    float vacc[8];
    // q
    {
        float acc[8];
        #pragma unroll
        for (int i = 0; i < 8; ++i) acc[i] = bq[col];
        for (int d = 0; d < 64; ++d) {
            float w = Wq[d * 64 + col];
            #pragma unroll
            for (int i = 0; i < 8; ++i) acc[i] = fmaf(xs[(rg + i) * 65 + d], w, acc[i]);
        }
        #pragma unroll
        for (int i = 0; i < 8; ++i) {
            size_t o = (size_t)(r0 + rg + i) * 64 + col;
            ushort h = f2bf(acc[i]);
            qh[o] = h;
            ql[o] = f2bf(acc[i] - bf2f(h));
        }
    }
    // k
    {
        float acc[8];
        #pragma unroll
        for (int i = 0; i < 8; ++i) acc[i] = bk[col];
        for (int d = 0; d < 64; ++d) {
            float w = Wk[d * 64 + col];
            #pragma unroll
            for (int i = 0; i < 8; ++i) acc[i] = fmaf(xs[(rg + i) * 65 + d], w, acc[i]);
        }
        #pragma unroll
        for (int i = 0; i < 8; ++i) {
            size_t o = (size_t)(r0 + rg + i) * 64 + col;
            ushort h = f2bf(acc[i]);
            kh[o] = h;
            kl[o] = f2bf(acc[i] - bf2f(h));
        }
    }
    // v (keep in regs, then LDS-transpose for coalesced vT store)
    {
        #pragma unroll
        for (int i = 0; i < 8; ++i) vacc[i] = bv[col];
        for (int d = 0; d < 64; ++d) {
            float w = Wv[d * 64 + col];
            #pragma unroll
            for (int i = 0; i < 8; ++i) vacc[i] = fmaf(xs[(rg + i) * 65 + d], w, vacc[i]);
        }
    }
    __syncthreads();                          // xs reads done; reuse as v staging
    #pragma unroll
    for (int i = 0; i < 8; ++i) xs[(rg + i) * 65 + col] = vacc[i];
    __syncthreads();
    const int bb = r0 >> 11;                  // batch
    const int n0 = r0 & 2047;                 // row within batch
    for (int idx = t; idx < 2048; idx += 256) {
        int d = idx >> 5, j = idx & 31;
        vt[((size_t)bb * 64 + d) * 2048 + n0 + j] = f2bf(xs[j * 65 + d]);
    }
}

// ---------------- Kernel 2: fused attention per 16-row block ----------------
// S row stride 2052: 4*2052%32==16 -> C-store 2-way; 2052%32==4 -> scans 2-way; %4==0 -> 16B-aligned b128 reads
#define SP 2052

__global__ __launch_bounds__(512, 2)
void attn_kernel(const ushort* __restrict__ qh, const ushort* __restrict__ ql,
                 const ushort* __restrict__ kh, const ushort* __restrict__ kl,
                 const ushort* __restrict__ vt, const int* __restrict__ adj,
                 const float* __restrict__ x,
                 const float* __restrict__ Wo, const float* __restrict__ bo,
                 const float* __restrict__ Wl, const float* __restrict__ bl,
                 float* __restrict__ y, float* __restrict__ attn)
{
    __shared__ float S[16 * SP];      // 131,328 B : scores -> exp values (unnormalized)
    __shared__ float red[512];
    __shared__ float mrow[16];
    __shared__ float rZ[16];
    __shared__ float cA[16][66];      // PV partials (K-half 0)
    __shared__ float cB[16][66];      // PV partials (K-half 1)
    __shared__ float cto[16][66];     // ctx @ Wo + bo
    __shared__ float xs[16][64];      // staged x rows for epilogue

    const int t    = threadIdx.x;
    const int lane = t & 63;
    const int wave = t >> 6;                  // 0..7
    const int b    = blockIdx.y;
    const int row0 = blockIdx.x * 16;

    const int la = lane & 15;                 // A-row / B-col / C-col index
    const int ak = (lane >> 4) * 8;           // K-offset within 32-chunk
    const int rb2 = (lane >> 4) * 4;          // C-row base

    // Q A-fragments (split hi/lo, K=64 -> two 32-chunks each)
    const size_t qoff = ((size_t)(b * NN + row0) + la) * 64 + ak;
    const s8v aqh0 = *(const s8v*)(qh + qoff);
    const s8v aqh1 = *(const s8v*)(qh + qoff + 32);
    const s8v aql0 = *(const s8v*)(ql + qoff);
    const s8v aql1 = *(const s8v*)(ql + qoff + 32);

    const ushort* kph = kh + (size_t)b * NN * 64;
    const ushort* kpl = kl + (size_t)b * NN * 64;
    const int*    ap  = adj + ((size_t)b * NN + row0) * NN;

    // ---- QK^T: wave w covers cols [w*256, w*256+256), 16 tiles of 16x16
    for (int tile = 0; tile < 16; ++tile) {
        const int c = wave * 256 + tile * 16;
        const size_t ko = (size_t)(c + la) * 64 + ak;   // K-row (c+la) as B^T column
        const s8v bh0 = *(const s8v*)(kph + ko);
        const s8v bh1 = *(const s8v*)(kph + ko + 32);
        const s8v bl0 = *(const s8v*)(kpl + ko);
        const s8v bl1 = *(const s8v*)(kpl + ko + 32);
        f32x4 acc = {0.f, 0.f, 0.f, 0.f};
        acc = __builtin_amdgcn_mfma_f32_16x16x32_bf16(aqh0, bh0, acc, 0, 0, 0);
        acc = __builtin_amdgcn_mfma_f32_16x16x32_bf16(aqh1, bh1, acc, 0, 0, 0);
        acc = __builtin_amdgcn_mfma_f32_16x16x32_bf16(aql0, bh0, acc, 0, 0, 0);
        acc = __builtin_amdgcn_mfma_f32_16x16x32_bf16(aql1, bh1, acc, 0, 0, 0);
        acc = __builtin_amdgcn_mfma_f32_16x16x32_bf16(aqh0, bl0, acc, 0, 0, 0);
        acc = __builtin_amdgcn_mfma_f32_16x16x32_bf16(aqh1, bl1, acc, 0, 0, 0);
        const int ccol = c + la;
        #pragma unroll
        for (int r = 0; r < 4; ++r) {
            int av = ap[(rb2 + r) * NN + ccol];
            S[(rb2 + r) * SP + ccol] = (av > 0) ? acc[r] * 0.125f : -1e9f;
        }
    }
    // stage x rows (independent of S)
    {
        const float* xp = x + (size_t)(b * NN + row0) * 64;
        for (int i2 = t; i2 < 1024; i2 += 512) xs[i2 >> 6][i2 & 63] = xp[i2];
    }
    __syncthreads();

    // ---- softmax: 32 threads per row
    {
        const int r = t >> 5, i = t & 31;
        float m = -3.0e38f;
        for (int c2 = i; c2 < NN; c2 += 32) m = fmaxf(m, S[r * SP + c2]);
        red[t] = m;
        __syncthreads();
        if (t < 16) {
            float mm = red[t * 32];
            for (int j = 1; j < 32; ++j) mm = fmaxf(mm, red[t * 32 + j]);
            mrow[t] = mm;
        }
        __syncthreads();
        const float mm = mrow[r];
        float sum = 0.f;
        for (int c2 = i; c2 < NN; c2 += 32) {
            float e = __expf(S[r * SP + c2] - mm);
            S[r * SP + c2] = e;                 // store unnormalized exp
            sum += e;
        }
        red[t] = sum;
        __syncthreads();
        if (t < 16) {
            float z = 0.f;
            for (int j = 0; j < 32; ++j) z += red[t * 32 + j];
            rZ[t] = 1.0f / z;
        }
        __syncthreads();
    }

    // ---- write normalized attn (coalesced fp32 stream; fire-and-forget overlaps PV)
    {
        float* aop = attn + ((size_t)b * NN + row0) * NN;
        for (int r = 0; r < 16; ++r) {
            const float rz = rZ[r];
            for (int c2 = t; c2 < NN; c2 += 512)
                aop[(size_t)r * NN + c2] = S[r * SP + c2] * rz;
        }
    }

    // ---- PV: ctx = P(unnorm) @ V. waves 0-3: K-half 0, waves 4-7: K-half 1; (wave&3) picks d-tile
    {
        const int half = wave >> 2;
        const int dt = (wave & 3) * 16;
        const ushort* vrow = vt + ((size_t)b * 64 + dt + la) * NN;  // vT row = V column (dt+la)
        f32x4 acc = {0.f, 0.f, 0.f, 0.f};
        const int kk0 = half * 1024;
        for (int kk = kk0; kk < kk0 + 1024; kk += 32) {
            const float* sp = &S[la * SP + kk + ak];
            s8v a;
            #pragma unroll
            for (int j = 0; j < 8; ++j) a[j] = (short)f2bf(sp[j]);
            const s8v bv8 = *(const s8v*)(vrow + kk + ak);
            acc = __builtin_amdgcn_mfma_f32_16x16x32_bf16(a, bv8, acc, 0, 0, 0);
        }
        float (*cbuf)[66] = half ? cB : cA;
        #pragma unroll
        for (int r = 0; r < 4; ++r) cbuf[rb2 + r][dt + la] = acc[r];
    }
    __syncthreads();

    // ---- ctxo = (ctx * 1/Z) @ Wo + bo
    for (int idx = t; idx < 1024; idx += 512) {
        const int r = idx >> 6, cg = idx & 63;
        const float rz = rZ[r];
        float a2 = bo[cg];
        for (int d = 0; d < 64; ++d) {
            float cv = (cA[r][d] + cB[r][d]) * rz;
            a2 = fmaf(cv, Wo[d * 64 + cg], a2);
        }
        cto[r][cg] = a2;
    }
    __syncthreads();

    // ---- y = relu([x, ctxo] @ Wl + bl)
    {
        float* yp = y + (size_t)(b * NN + row0) * 64;
        for (int idx = t; idx < 1024; idx += 512) {
            const int r = idx >> 6, cg = idx & 63;
            float a2 = bl[cg];
            for (int d = 0; d < 64; ++d) a2 = fmaf(xs[r][d], Wl[d * 64 + cg], a2);
            for (int d = 0; d < 64; ++d) a2 = fmaf(cto[r][d], Wl[(64 + d) * 64 + cg], a2);
            yp[(size_t)r * 64 + cg] = fmaxf(a2, 0.f);
        }
    }
}

extern "C" void kernel_launch(void* const* d_in, const int* in_sizes, int n_in,
                              void* d_out, int out_size, void* d_ws, size_t ws_size,
                              hipStream_t stream) {
    const float* x  = (const float*)d_in[0];
    const int*   adj = (const int*)d_in[1];
    const float* Wq = (const float*)d_in[2];
    const float* bq = (const float*)d_in[3];
    const float* Wk = (const float*)d_in[4];
    const float* bk = (const float*)d_in[5];
    const float* Wv = (const float*)d_in[6];
    const float* bv = (const float*)d_in[7];
    const float* Wo = (const float*)d_in[8];
    const float* bo = (const float*)d_in[9];
    const float* Wl = (const float*)d_in[10];
    const float* bl = (const float*)d_in[11];

    float* y    = (float*)d_out;
    float* attn = (float*)d_out + (size_t)NB * NN * DI;

    const size_t QSZ = (size_t)NB * NN * DI;          // 2,097,152 elems
    ushort* qh = (ushort*)d_ws;
    ushort* ql = qh + QSZ;
    ushort* kh = ql + QSZ;
    ushort* kl = kh + QSZ;
    ushort* vt = kl + QSZ;                            // total ws use: 5*4 MB = 21 MB

    qkv_kernel<<<1024, 256, 0, stream>>>(x, Wq, bq, Wk, bk, Wv, bv, qh, ql, kh, kl, vt);
    attn_kernel<<<dim3(NN / 16, NB), 512, 0, stream>>>(qh, ql, kh, kl, vt, adj, x,
                                                       Wo, bo, Wl, bl, y, attn);
}

// Round 2
// 709.731 us; speedup vs baseline: 1.0493x; 1.0493x over previous
//
#include <hip/hip_runtime.h>
#include <hip/hip_bf16.h>

// GraphConv: masked single-head attention, B=16, N=2048, D=64.
// Inputs (fp32 unless noted): x[B,N,64], adj[B,N,N] int32, Wq,bq,Wk,bk,Wv,bv,Wo,bo (64x64/64), Wl[128,64], bl[64]
// Outputs (fp32, concat): y[B,N,64] then attn[B,N,N]

#define NB 16
#define NN 2048
#define DI 64

using s8v   = __attribute__((ext_vector_type(8))) short;   // 8 bf16 (4 VGPR) MFMA frag
using f32x4 = __attribute__((ext_vector_type(4))) float;

__device__ __forceinline__ ushort f2bf(float f) {
    __hip_bfloat16 h = __float2bfloat16(f);   // RNE
    return *reinterpret_cast<ushort*>(&h);
}
__device__ __forceinline__ float bf2f(ushort u) {
    union { uint32_t u; float f; } v; v.u = ((uint32_t)u) << 16;
    return v.f;
}

// ---------------- Kernel 1: q,k (split bf16 hi/lo, row-major) and vT (bf16, [b][d][n]) ----------------
__global__ __launch_bounds__(256)
void qkv_kernel(const float* __restrict__ x,
                const float* __restrict__ Wq, const float* __restrict__ bq,
                const float* __restrict__ Wk, const float* __restrict__ bk,
                const float* __restrict__ Wv, const float* __restrict__ bv,
                ushort* __restrict__ qh, ushort* __restrict__ ql,
                ushort* __restrict__ kh, ushort* __restrict__ kl,
                ushort* __restrict__ vt)
{
    __shared__ float xs[32 * 65];            // padded: bank-conflict-free transpose
    const int t  = threadIdx.x;
    const int r0 = blockIdx.x * 32;          // global row (32 rows/block; 2048%32==0 so batch-aligned)
    for (int idx = t; idx < 2048; idx += 256)
        xs[(idx >> 6) * 65 + (idx & 63)] = x[(size_t)r0 * 64 + idx];
    __syncthreads();

    const int col = t & 63;
    const int rg  = (t >> 6) * 8;            // 8 rows per thread-group

    float vacc[8];
    // q
    {
        float acc[8];
        #pragma unroll
        for (int i = 0; i < 8; ++i) acc[i] = bq[col];
        for (int d = 0; d < 64; ++d) {
            float w = Wq[d * 64 + col];
            #pragma unroll
            for (int i = 0; i < 8; ++i) acc[i] = fmaf(xs[(rg + i) * 65 + d], w, acc[i]);
        }
        #pragma unroll
        for (int i = 0; i < 8; ++i) {
            size_t o = (size_t)(r0 + rg + i) * 64 + col;
            ushort h = f2bf(acc[i]);
            qh[o] = h;
            ql[o] = f2bf(acc[i] - bf2f(h));
        }
    }
    // k
    {
        float acc[8];
        #pragma unroll
        for (int i = 0; i < 8; ++i) acc[i] = bk[col];
        for (int d = 0; d < 64; ++d) {
            float w = Wk[d * 64 + col];
            #pragma unroll
            for (int i = 0; i < 8; ++i) acc[i] = fmaf(xs[(rg + i) * 65 + d], w, acc[i]);
        }
        #pragma unroll
        for (int i = 0; i < 8; ++i) {
            size_t o = (size_t)(r0 + rg + i) * 64 + col;
            ushort h = f2bf(acc[i]);
            kh[o] = h;
            kl[o] = f2bf(acc[i] - bf2f(h));
        }
    }
    // v (keep in regs, then LDS-transpose for coalesced vT store)
    {
        #pragma unroll
        for (int i = 0; i < 8; ++i) vacc[i] = bv[col];
        for (int d = 0; d < 64; ++d) {
            float w = Wv[d * 64 + col];
            #pragma unroll
            for (int i = 0; i < 8; ++i) vacc[i] = fmaf(xs[(rg + i) * 65 + d], w, vacc[i]);
        }
    }
    __syncthreads();                          // xs reads done; reuse as v staging
    #pragma unroll
    for (int i = 0; i < 8; ++i) xs[(rg + i) * 65 + col] = vacc[i];
    __syncthreads();
    const int bb = r0 >> 11;                  // batch
    const int n0 = r0 & 2047;                 // row within batch
    for (int idx = t; idx < 2048; idx += 256) {
        int d = idx >> 5, j = idx & 31;
        vt[((size_t)bb * 64 + d) * 2048 + n0 + j] = f2bf(xs[j * 65 + d]);
    }
}

// ---------------- Kernel 2: fused attention per 16-row block ----------------
// S16 stride 2056 ushort = 4112 B/row; 4112 % 128 = 16 -> 4-bank shift/row, rows 16B-aligned for b128
#define SP2 2056

__global__ __launch_bounds__(512)
void attn_kernel(const ushort* __restrict__ qh, const ushort* __restrict__ ql,
                 const ushort* __restrict__ kh, const ushort* __restrict__ kl,
                 const ushort* __restrict__ vt, const int* __restrict__ adj,
                 const float* __restrict__ x,
                 const float* __restrict__ Wo, const float* __restrict__ bo,
                 const float* __restrict__ Wl, const float* __restrict__ bl,
                 float* __restrict__ y, float* __restrict__ attn)
{
    __shared__ ushort S16[16 * SP2];  // 65,792 B : unnormalized exp values (bf16)
    __shared__ float cA[16][66];      // PV partials (K-half 0)
    __shared__ float cB[16][66];      // PV partials (K-half 1)
    __shared__ float cto[16][66];     // ctx @ Wo + bo
    __shared__ float mbuf[8][16];     // per-wave row maxima
    __shared__ float zbuf[8][16];     // per-wave row sums
    __shared__ float mrow[16];
    __shared__ float rZ[16];
    // total LDS = 79,616 B -> 2 blocks/CU

    const int t    = threadIdx.x;
    const int lane = t & 63;
    const int wave = t >> 6;                  // 0..7

    // XCD-bijective swizzle: batch = (bid&7) + 8*(i>>7) so each XCD serves 2 batches (K/V L2-resident)
    const int bid = blockIdx.x;
    const int i0  = bid >> 3;
    const int b   = (bid & 7) + 8 * (i0 >> 7);
    const int row0 = (i0 & 127) * 16;

    const int la  = lane & 15;                // A-row / B-col / C-col index
    const int ak  = (lane >> 4) * 8;          // K-offset within 32-chunk
    const int rb2 = (lane >> 4) * 4;          // C-row base

    // Q A-fragments (split hi/lo, K=64 -> two 32-chunks each)
    const size_t qoff = ((size_t)(b * NN + row0) + la) * 64 + ak;
    const s8v aqh0 = *(const s8v*)(qh + qoff);
    const s8v aqh1 = *(const s8v*)(qh + qoff + 32);
    const s8v aql0 = *(const s8v*)(ql + qoff);
    const s8v aql1 = *(const s8v*)(ql + qoff + 32);

    const ushort* kph = kh + (size_t)b * NN * 64;
    const ushort* kpl = kl + (size_t)b * NN * 64;
    const int*    ap  = adj + ((size_t)b * NN + row0) * NN;

    // ---- QK^T into registers: wave w covers cols [w*256, w*256+256), 16 tiles of 16x16
    f32x4 acc[16];
    int   adjv[16][4];                        // prefetched mask values (consumed after MFMA loop)
    #pragma unroll
    for (int tile = 0; tile < 16; ++tile) {
        const int c = wave * 256 + tile * 16;
        #pragma unroll
        for (int r = 0; r < 4; ++r) adjv[tile][r] = ap[(rb2 + r) * NN + c + la];
        const size_t ko = (size_t)(c + la) * 64 + ak;   // K-row (c+la) as B^T column
        const s8v bh0 = *(const s8v*)(kph + ko);
        const s8v bh1 = *(const s8v*)(kph + ko + 32);
        const s8v bl0 = *(const s8v*)(kpl + ko);
        const s8v bl1 = *(const s8v*)(kpl + ko + 32);
        f32x4 a = {0.f, 0.f, 0.f, 0.f};
        a = __builtin_amdgcn_mfma_f32_16x16x32_bf16(aqh0, bh0, a, 0, 0, 0);
        a = __builtin_amdgcn_mfma_f32_16x16x32_bf16(aqh1, bh1, a, 0, 0, 0);
        a = __builtin_amdgcn_mfma_f32_16x16x32_bf16(aql0, bh0, a, 0, 0, 0);
        a = __builtin_amdgcn_mfma_f32_16x16x32_bf16(aql1, bh1, a, 0, 0, 0);
        a = __builtin_amdgcn_mfma_f32_16x16x32_bf16(aqh0, bl0, a, 0, 0, 0);
        a = __builtin_amdgcn_mfma_f32_16x16x32_bf16(aqh1, bl1, a, 0, 0, 0);
        acc[tile] = a;
    }
    // mask + scale (1/sqrt(64))
    #pragma unroll
    for (int tile = 0; tile < 16; ++tile) {
        #pragma unroll
        for (int r = 0; r < 4; ++r)
            acc[tile][r] = (adjv[tile][r] > 0) ? acc[tile][r] * 0.125f : -1e9f;
    }

    // ---- softmax, register-resident. Lane holds rows rb2..rb2+3 over cols {wave*256 + tile*16 + la}
    float vm[4];
    #pragma unroll
    for (int r = 0; r < 4; ++r) {
        float m = acc[0][r];
        #pragma unroll
        for (int tile = 1; tile < 16; ++tile) m = fmaxf(m, acc[tile][r]);
        vm[r] = m;
    }
    #pragma unroll
    for (int off = 1; off < 16; off <<= 1) {
        #pragma unroll
        for (int r = 0; r < 4; ++r) vm[r] = fmaxf(vm[r], __shfl_xor(vm[r], off));
    }
    if (la == 0) {
        #pragma unroll
        for (int r = 0; r < 4; ++r) mbuf[wave][rb2 + r] = vm[r];
    }
    __syncthreads();
    if (t < 16) {
        float m = mbuf[0][t];
        #pragma unroll
        for (int w = 1; w < 8; ++w) m = fmaxf(m, mbuf[w][t]);
        mrow[t] = m;
    }
    __syncthreads();

    float gm[4], vs[4];
    #pragma unroll
    for (int r = 0; r < 4; ++r) { gm[r] = mrow[rb2 + r]; vs[r] = 0.f; }
    #pragma unroll
    for (int tile = 0; tile < 16; ++tile) {
        const int c = wave * 256 + tile * 16;
        #pragma unroll
        for (int r = 0; r < 4; ++r) {
            float e = __expf(acc[tile][r] - gm[r]);
            vs[r] += e;
            S16[(rb2 + r) * SP2 + c + la] = f2bf(e);
        }
    }
    #pragma unroll
    for (int off = 1; off < 16; off <<= 1) {
        #pragma unroll
        for (int r = 0; r < 4; ++r) vs[r] += __shfl_xor(vs[r], off);
    }
    if (la == 0) {
        #pragma unroll
        for (int r = 0; r < 4; ++r) zbuf[wave][rb2 + r] = vs[r];
    }
    __syncthreads();                          // covers S16 stores + zbuf
    if (t < 16) {
        float z = 0.f;
        #pragma unroll
        for (int w = 0; w < 8; ++w) z += zbuf[w][t];
        rZ[t] = 1.0f / z;
    }
    __syncthreads();

    // ---- write normalized attn (float4 stream; stores drain during PV)
    {
        float* aop = attn + ((size_t)b * NN + row0) * NN;
        for (int r = 0; r < 16; ++r) {
            const float rz = rZ[r];
            const uint2 u = *(const uint2*)(&S16[r * SP2 + 4 * t]);   // 4 bf16, 8B aligned
            float4 o;
            o.x = bf2f((ushort)(u.x))       * rz;
            o.y = bf2f((ushort)(u.x >> 16)) * rz;
            o.z = bf2f((ushort)(u.y))       * rz;
            o.w = bf2f((ushort)(u.y >> 16)) * rz;
            *(float4*)(aop + (size_t)r * NN + 4 * t) = o;
        }
    }

    // ---- PV: ctx = P(unnorm) @ V. waves 0-3: K-half 0, waves 4-7: K-half 1; (wave&3) picks d-tile
    {
        const int half = wave >> 2;
        const int dt   = (wave & 3) * 16;
        const ushort* vrow = vt + ((size_t)b * 64 + dt + la) * NN;  // vT row = V column (dt+la)
        f32x4 a = {0.f, 0.f, 0.f, 0.f};
        const int kk0 = half * 1024;
        #pragma unroll 4
        for (int kk = kk0; kk < kk0 + 1024; kk += 32) {
            const s8v pa  = *(const s8v*)(&S16[la * SP2 + kk + ak]);  // bf16 exp, direct b128
            const s8v bv8 = *(const s8v*)(vrow + kk + ak);
            a = __builtin_amdgcn_mfma_f32_16x16x32_bf16(pa, bv8, a, 0, 0, 0);
        }
        float (*cbuf)[66] = half ? cB : cA;
        #pragma unroll
        for (int r = 0; r < 4; ++r) cbuf[rb2 + r][dt + la] = a[r];
    }
    __syncthreads();

    // ---- ctxo = (ctx * 1/Z) @ Wo + bo
    for (int idx = t; idx < 1024; idx += 512) {
        const int r = idx >> 6, cg = idx & 63;
        const float rz = rZ[r];
        float a2 = bo[cg];
        for (int d = 0; d < 64; ++d) {
            float cv = (cA[r][d] + cB[r][d]) * rz;
            a2 = fmaf(cv, Wo[d * 64 + cg], a2);
        }
        cto[r][cg] = a2;
    }
    __syncthreads();

    // ---- y = relu([x, ctxo] @ Wl + bl)   (x rows via L1 broadcast; no LDS staging)
    {
        const float* xp = x + (size_t)(b * NN + row0) * 64;
        float*       yp = y + (size_t)(b * NN + row0) * 64;
        for (int idx = t; idx < 1024; idx += 512) {
            const int r = idx >> 6, cg = idx & 63;
            float a2 = bl[cg];
            for (int d = 0; d < 64; ++d) a2 = fmaf(xp[r * 64 + d], Wl[d * 64 + cg], a2);
            for (int d = 0; d < 64; ++d) a2 = fmaf(cto[r][d], Wl[(64 + d) * 64 + cg], a2);
            yp[(size_t)r * 64 + cg] = fmaxf(a2, 0.f);
        }
    }
}

extern "C" void kernel_launch(void* const* d_in, const int* in_sizes, int n_in,
                              void* d_out, int out_size, void* d_ws, size_t ws_size,
                              hipStream_t stream) {
    const float* x  = (const float*)d_in[0];
    const int*   adj = (const int*)d_in[1];
    const float* Wq = (const float*)d_in[2];
    const float* bq = (const float*)d_in[3];
    const float* Wk = (const float*)d_in[4];
    const float* bk = (const float*)d_in[5];
    const float* Wv = (const float*)d_in[6];
    const float* bv = (const float*)d_in[7];
    const float* Wo = (const float*)d_in[8];
    const float* bo = (const float*)d_in[9];
    const float* Wl = (const float*)d_in[10];
    const float* bl = (const float*)d_in[11];

    float* y    = (float*)d_out;
    float* attn = (float*)d_out + (size_t)NB * NN * DI;

    const size_t QSZ = (size_t)NB * NN * DI;          // 2,097,152 elems
    ushort* qh = (ushort*)d_ws;
    ushort* ql = qh + QSZ;
    ushort* kh = ql + QSZ;
    ushort* kl = kh + QSZ;
    ushort* vt = kl + QSZ;                            // total ws use: 5*4 MB = 21 MB

    qkv_kernel<<<1024, 256, 0, stream>>>(x, Wq, bq, Wk, bk, Wv, bv, qh, ql, kh, kl, vt);
    attn_kernel<<<NB * (NN / 16), 512, 0, stream>>>(qh, ql, kh, kl, vt, adj, x,
                                                    Wo, bo, Wl, bl, y, attn);
}

// Round 3
// 690.530 us; speedup vs baseline: 1.0785x; 1.0278x over previous
//
#include <hip/hip_runtime.h>
#include <hip/hip_bf16.h>

// GraphConv: masked single-head attention, B=16, N=2048, D=64.
// Inputs (fp32 unless noted): x[B,N,64], adj[B,N,N] int32, Wq,bq,Wk,bk,Wv,bv,Wo,bo (64x64/64), Wl[128,64], bl[64]
// Outputs (fp32, concat): y[B,N,64] then attn[B,N,N]

#define NB 16
#define NN 2048
#define DI 64

using s8v   = __attribute__((ext_vector_type(8))) short;   // 8 bf16 (4 VGPR) MFMA frag
using f32x4 = __attribute__((ext_vector_type(4))) float;

__device__ __forceinline__ ushort f2bf(float f) {
    __hip_bfloat16 h = __float2bfloat16(f);   // RNE
    return *reinterpret_cast<ushort*>(&h);
}
__device__ __forceinline__ float bf2f(ushort u) {
    union { uint32_t u; float f; } v; v.u = ((uint32_t)u) << 16;
    return v.f;
}

// ---------------- Kernel 1: q,k (split bf16 hi/lo, row-major) and vT (bf16, [b][d][n]) ----------------
// q is pre-scaled by 1/sqrt(D) = 0.125 (exact power of 2; split unaffected).
__global__ __launch_bounds__(256)
void qkv_kernel(const float* __restrict__ x,
                const float* __restrict__ Wq, const float* __restrict__ bq,
                const float* __restrict__ Wk, const float* __restrict__ bk,
                const float* __restrict__ Wv, const float* __restrict__ bv,
                ushort* __restrict__ qh, ushort* __restrict__ ql,
                ushort* __restrict__ kh, ushort* __restrict__ kl,
                ushort* __restrict__ vt)
{
    __shared__ float xs[32 * 65];            // padded: bank-conflict-free transpose
    const int t  = threadIdx.x;
    const int r0 = blockIdx.x * 32;          // global row (32 rows/block; 2048%32==0 so batch-aligned)
    for (int idx = t; idx < 2048; idx += 256)
        xs[(idx >> 6) * 65 + (idx & 63)] = x[(size_t)r0 * 64 + idx];
    __syncthreads();

    const int col = t & 63;
    const int rg  = (t >> 6) * 8;            // 8 rows per thread-group

    float vacc[8];
    // q (scaled by 0.125)
    {
        float acc[8];
        #pragma unroll
        for (int i = 0; i < 8; ++i) acc[i] = bq[col];
        for (int d = 0; d < 64; ++d) {
            float w = Wq[d * 64 + col];
            #pragma unroll
            for (int i = 0; i < 8; ++i) acc[i] = fmaf(xs[(rg + i) * 65 + d], w, acc[i]);
        }
        #pragma unroll
        for (int i = 0; i < 8; ++i) {
            size_t o = (size_t)(r0 + rg + i) * 64 + col;
            float aq = acc[i] * 0.125f;
            ushort h = f2bf(aq);
            qh[o] = h;
            ql[o] = f2bf(aq - bf2f(h));
        }
    }
    // k
    {
        float acc[8];
        #pragma unroll
        for (int i = 0; i < 8; ++i) acc[i] = bk[col];
        for (int d = 0; d < 64; ++d) {
            float w = Wk[d * 64 + col];
            #pragma unroll
            for (int i = 0; i < 8; ++i) acc[i] = fmaf(xs[(rg + i) * 65 + d], w, acc[i]);
        }
        #pragma unroll
        for (int i = 0; i < 8; ++i) {
            size_t o = (size_t)(r0 + rg + i) * 64 + col;
            ushort h = f2bf(acc[i]);
            kh[o] = h;
            kl[o] = f2bf(acc[i] - bf2f(h));
        }
    }
    // v (keep in regs, then LDS-transpose for coalesced vT store)
    {
        #pragma unroll
        for (int i = 0; i < 8; ++i) vacc[i] = bv[col];
        for (int d = 0; d < 64; ++d) {
            float w = Wv[d * 64 + col];
            #pragma unroll
            for (int i = 0; i < 8; ++i) vacc[i] = fmaf(xs[(rg + i) * 65 + d], w, vacc[i]);
        }
    }
    __syncthreads();                          // xs reads done; reuse as v staging
    #pragma unroll
    for (int i = 0; i < 8; ++i) xs[(rg + i) * 65 + col] = vacc[i];
    __syncthreads();
    const int bb = r0 >> 11;                  // batch
    const int n0 = r0 & 2047;                 // row within batch
    for (int idx = t; idx < 2048; idx += 256) {
        int d = idx >> 5, j = idx & 31;
        vt[((size_t)bb * 64 + d) * 2048 + n0 + j] = f2bf(xs[j * 65 + d]);
    }
}

// ---------------- Kernel 2: fused attention per 16-row block ----------------
// S16 stride 2056 ushort = 4112 B/row; rows 16B-aligned for b128; 4-bank shift per row
#define SP2 2056

__global__ __launch_bounds__(512, 4)     // force <=128 unified regs -> 2 blocks/CU
void attn_kernel(const ushort* __restrict__ qh, const ushort* __restrict__ ql,
                 const ushort* __restrict__ kh, const ushort* __restrict__ kl,
                 const ushort* __restrict__ vt, const int* __restrict__ adj,
                 const float* __restrict__ x,
                 const float* __restrict__ Wo, const float* __restrict__ bo,
                 const float* __restrict__ Wl, const float* __restrict__ bl,
                 float* __restrict__ y, float* __restrict__ attn)
{
    __shared__ ushort S16[16 * SP2];  // 65,792 B : unnormalized exp values (bf16)
    __shared__ float cA[16][66];      // PV partials (K-half 0)
    __shared__ float cB[16][66];      // PV partials (K-half 1)
    __shared__ float cto[16][66];     // ctx @ Wo + bo
    __shared__ float mbuf[8][16];     // per-wave row maxima
    __shared__ float zbuf[8][16];     // per-wave row sums
    __shared__ float mrow[16];
    __shared__ float rZ[16];
    // total LDS = 79,616 B -> 2 blocks/CU

    const int t    = threadIdx.x;
    const int lane = t & 63;
    const int wave = t >> 6;                  // 0..7

    // XCD-bijective swizzle: batch = (bid&7) + 8*(i>>7) so each XCD serves 2 batches (K/V L2-resident)
    const int bid = blockIdx.x;
    const int i0  = bid >> 3;
    const int b   = (bid & 7) + 8 * (i0 >> 7);
    const int row0 = (i0 & 127) * 16;

    const int la  = lane & 15;                // A-row / B-col / C-col index
    const int ak  = (lane >> 4) * 8;          // K-offset within 32-chunk
    const int rb2 = (lane >> 4) * 4;          // C-row base

    const int*    ap  = adj + ((size_t)b * NN + row0) * NN;

    // ---- Phase A: compress this wave's 16x256 adj region into ballot bitmasks.
    // Iter i: coalesced 64-int load of (row i>>2, cols wave*256 + (i&3)*64 ..+63); ballot -> lane i.
    uint32_t m_lo = 0, m_hi = 0;
    #pragma unroll
    for (int i = 0; i < 64; ++i) {
        int v = ap[(size_t)(i >> 2) * NN + wave * 256 + (i & 3) * 64 + lane];
        unsigned long long bm = __ballot(v > 0);
        m_lo = (lane == i) ? (uint32_t)bm : m_lo;
        m_hi = (lane == i) ? (uint32_t)(bm >> 32) : m_hi;
    }
    // lane l now holds mask bits for row (l>>2), col-group (l&3) of this wave's 256-col slice.

    // Q A-fragments (split hi/lo, K=64 -> two 32-chunks each)
    const size_t qoff = ((size_t)(b * NN + row0) + la) * 64 + ak;
    const s8v aqh0 = *(const s8v*)(qh + qoff);
    const s8v aqh1 = *(const s8v*)(qh + qoff + 32);
    const s8v aql0 = *(const s8v*)(ql + qoff);
    const s8v aql1 = *(const s8v*)(ql + qoff + 32);

    const ushort* kph = kh + (size_t)b * NN * 64;
    const ushort* kpl = kl + (size_t)b * NN * 64;

    // ---- QK^T into registers: wave w covers cols [w*256, w*256+256), 16 tiles of 16x16
    f32x4 acc[16];
    #pragma unroll
    for (int tile = 0; tile < 16; ++tile) {
        const int c = wave * 256 + tile * 16;
        const size_t ko = (size_t)(c + la) * 64 + ak;   // K-row (c+la) as B^T column
        const s8v bh0 = *(const s8v*)(kph + ko);
        const s8v bh1 = *(const s8v*)(kph + ko + 32);
        const s8v bl0 = *(const s8v*)(kpl + ko);
        const s8v bl1 = *(const s8v*)(kpl + ko + 32);
        f32x4 a = {0.f, 0.f, 0.f, 0.f};
        a = __builtin_amdgcn_mfma_f32_16x16x32_bf16(aqh0, bh0, a, 0, 0, 0);
        a = __builtin_amdgcn_mfma_f32_16x16x32_bf16(aqh1, bh1, a, 0, 0, 0);
        a = __builtin_amdgcn_mfma_f32_16x16x32_bf16(aql0, bh0, a, 0, 0, 0);
        a = __builtin_amdgcn_mfma_f32_16x16x32_bf16(aql1, bh1, a, 0, 0, 0);
        a = __builtin_amdgcn_mfma_f32_16x16x32_bf16(aqh0, bl0, a, 0, 0, 0);
        a = __builtin_amdgcn_mfma_f32_16x16x32_bf16(aqh1, bl1, a, 0, 0, 0);
        // mask from ballots: bit (row rb2+r, col tile*16+la) lives in lane (rb2+r)*4 + (tile>>2),
        // word half = tile&2, bit = (tile&1)*16 + la.   (q pre-scaled, so pure select)
        #pragma unroll
        for (int r = 0; r < 4; ++r) {
            int addr = ((rb2 + r) * 4 + (tile >> 2)) * 4;
            uint32_t pm = (uint32_t)__builtin_amdgcn_ds_bpermute(
                              addr, (int)((tile & 2) ? m_hi : m_lo));
            int bit = (pm >> (((tile & 1) << 4) + la)) & 1;
            a[r] = bit ? a[r] : -1e9f;
        }
        acc[tile] = a;
    }

    // ---- softmax, register-resident. Lane holds rows rb2..rb2+3 over cols {wave*256 + tile*16 + la}
    float vm[4];
    #pragma unroll
    for (int r = 0; r < 4; ++r) {
        float m = acc[0][r];
        #pragma unroll
        for (int tile = 1; tile < 16; ++tile) m = fmaxf(m, acc[tile][r]);
        vm[r] = m;
    }
    #pragma unroll
    for (int off = 1; off < 16; off <<= 1) {
        #pragma unroll
        for (int r = 0; r < 4; ++r) vm[r] = fmaxf(vm[r], __shfl_xor(vm[r], off));
    }
    if (la == 0) {
        #pragma unroll
        for (int r = 0; r < 4; ++r) mbuf[wave][rb2 + r] = vm[r];
    }
    __syncthreads();
    if (t < 16) {
        float m = mbuf[0][t];
        #pragma unroll
        for (int w = 1; w < 8; ++w) m = fmaxf(m, mbuf[w][t]);
        mrow[t] = m;
    }
    __syncthreads();

    float gm[4], vs[4];
    #pragma unroll
    for (int r = 0; r < 4; ++r) { gm[r] = mrow[rb2 + r]; vs[r] = 0.f; }
    #pragma unroll
    for (int tile = 0; tile < 16; ++tile) {
        const int c = wave * 256 + tile * 16;
        #pragma unroll
        for (int r = 0; r < 4; ++r) {
            float e = __expf(acc[tile][r] - gm[r]);
            vs[r] += e;
            S16[(rb2 + r) * SP2 + c + la] = f2bf(e);
        }
    }
    #pragma unroll
    for (int off = 1; off < 16; off <<= 1) {
        #pragma unroll
        for (int r = 0; r < 4; ++r) vs[r] += __shfl_xor(vs[r], off);
    }
    if (la == 0) {
        #pragma unroll
        for (int r = 0; r < 4; ++r) zbuf[wave][rb2 + r] = vs[r];
    }
    __syncthreads();                          // covers S16 stores + zbuf
    if (t < 16) {
        float z = 0.f;
        #pragma unroll
        for (int w = 0; w < 8; ++w) z += zbuf[w][t];
        rZ[t] = 1.0f / z;
    }
    __syncthreads();

    // ---- write normalized attn (float4 stream; stores drain during PV)
    {
        float* aop = attn + ((size_t)b * NN + row0) * NN;
        for (int r = 0; r < 16; ++r) {
            const float rz = rZ[r];
            const uint2 u = *(const uint2*)(&S16[r * SP2 + 4 * t]);   // 4 bf16, 8B aligned
            float4 o;
            o.x = bf2f((ushort)(u.x))       * rz;
            o.y = bf2f((ushort)(u.x >> 16)) * rz;
            o.z = bf2f((ushort)(u.y))       * rz;
            o.w = bf2f((ushort)(u.y >> 16)) * rz;
            *(float4*)(aop + (size_t)r * NN + 4 * t) = o;
        }
    }

    // ---- PV: ctx = P(unnorm) @ V. waves 0-3: K-half 0, waves 4-7: K-half 1; (wave&3) picks d-tile
    {
        const int half = wave >> 2;
        const int dt   = (wave & 3) * 16;
        const ushort* vrow = vt + ((size_t)b * 64 + dt + la) * NN;  // vT row = V column (dt+la)
        f32x4 a = {0.f, 0.f, 0.f, 0.f};
        const int kk0 = half * 1024;
        #pragma unroll 4
        for (int kk = kk0; kk < kk0 + 1024; kk += 32) {
            const s8v pa  = *(const s8v*)(&S16[la * SP2 + kk + ak]);  // bf16 exp, direct b128
            const s8v bv8 = *(const s8v*)(vrow + kk + ak);
            a = __builtin_amdgcn_mfma_f32_16x16x32_bf16(pa, bv8, a, 0, 0, 0);
        }
        float (*cbuf)[66] = half ? cB : cA;
        #pragma unroll
        for (int r = 0; r < 4; ++r) cbuf[rb2 + r][dt + la] = a[r];
    }
    __syncthreads();

    // ---- ctxo = (ctx * 1/Z) @ Wo + bo
    for (int idx = t; idx < 1024; idx += 512) {
        const int r = idx >> 6, cg = idx & 63;
        const float rz = rZ[r];
        float a2 = bo[cg];
        for (int d = 0; d < 64; ++d) {
            float cv = (cA[r][d] + cB[r][d]) * rz;
            a2 = fmaf(cv, Wo[d * 64 + cg], a2);
        }
        cto[r][cg] = a2;
    }
    __syncthreads();

    // ---- y = relu([x, ctxo] @ Wl + bl)   (x rows via L1 broadcast; no LDS staging)
    {
        const float* xp = x + (size_t)(b * NN + row0) * 64;
        float*       yp = y + (size_t)(b * NN + row0) * 64;
        for (int idx = t; idx < 1024; idx += 512) {
            const int r = idx >> 6, cg = idx & 63;
            float a2 = bl[cg];
            for (int d = 0; d < 64; ++d) a2 = fmaf(xp[r * 64 + d], Wl[d * 64 + cg], a2);
            for (int d = 0; d < 64; ++d) a2 = fmaf(cto[r][d], Wl[(64 + d) * 64 + cg], a2);
            yp[(size_t)r * 64 + cg] = fmaxf(a2, 0.f);
        }
    }
}

extern "C" void kernel_launch(void* const* d_in, const int* in_sizes, int n_in,
                              void* d_out, int out_size, void* d_ws, size_t ws_size,
                              hipStream_t stream) {
    const float* x  = (const float*)d_in[0];
    const int*   adj = (const int*)d_in[1];
    const float* Wq = (const float*)d_in[2];
    const float* bq = (const float*)d_in[3];
    const float* Wk = (const float*)d_in[4];
    const float* bk = (const float*)d_in[5];
    const float* Wv = (const float*)d_in[6];
    const float* bv = (const float*)d_in[7];
    const float* Wo = (const float*)d_in[8];
    const float* bo = (const float*)d_in[9];
    const float* Wl = (const float*)d_in[10];
    const float* bl = (const float*)d_in[11];

    float* y    = (float*)d_out;
    float* attn = (float*)d_out + (size_t)NB * NN * DI;

    const size_t QSZ = (size_t)NB * NN * DI;          // 2,097,152 elems
    ushort* qh = (ushort*)d_ws;
    ushort* ql = qh + QSZ;
    ushort* kh = ql + QSZ;
    ushort* kl = kh + QSZ;
    ushort* vt = kl + QSZ;                            // total ws use: 5*4 MB = 21 MB

    qkv_kernel<<<1024, 256, 0, stream>>>(x, Wq, bq, Wk, bk, Wv, bv, qh, ql, kh, kl, vt);
    attn_kernel<<<NB * (NN / 16), 512, 0, stream>>>(qh, ql, kh, kl, vt, adj, x,
                                                    Wo, bo, Wl, bl, y, attn);
}